// Round 1
// baseline (56.148 us; speedup 1.0000x reference)
//
#include <hip/hip_runtime.h>

// DividedModel: 64 towers of Dense(32,64)+ReLU -> 64x64+ReLU -> 64x64+ReLU -> 64x1
// Fused bf16-MFMA kernel. One block = one tower x 512 batch rows (8 tiles of 64).
// 4 waves/block, each wave owns 16 rows; weights live in registers (B-frags),
// inter-layer activations round-trip through a per-wave LDS region.

typedef float  f32x4 __attribute__((ext_vector_type(4)));
typedef short  bf8   __attribute__((ext_vector_type(8)));

static constexpr int Bsz  = 16384;
static constexpr int Idim = 32;
static constexpr int Odim = 64;
static constexpr int BPT  = 32;                 // blocks per tower
static constexpr int ROWTILES = (Bsz / 64) / BPT; // 8 tiles of 64 rows per block
static constexpr int P    = 72;                 // LDS row pitch (bf16 elems); 144B rows: 16B-aligned, 2-way bank alias (free)

__device__ __forceinline__ unsigned short f2bf(float f) {
    unsigned int u = __builtin_bit_cast(unsigned int, f);
    unsigned int r = u + 0x7FFFu + ((u >> 16) & 1u);   // RNE truncate f32 -> bf16
    return (unsigned short)(r >> 16);
}

__global__ __launch_bounds__(256) void towers_kernel(
    const float* __restrict__ x,
    const float* __restrict__ W0, const float* __restrict__ b0,
    const float* __restrict__ W1, const float* __restrict__ b1,
    const float* __restrict__ W2, const float* __restrict__ b2,
    const float* __restrict__ W3, const float* __restrict__ b3,
    float* __restrict__ out)
{
    __shared__ __align__(16) unsigned short Wt0[64 * P];  // Wt0[n][i] = W0[o][i][n]
    __shared__ __align__(16) unsigned short Wt1[64 * P];  // Wt1[n][h] = W1[o][h][n]
    __shared__ __align__(16) unsigned short Wt2[64 * P];
    __shared__ __align__(16) unsigned short Hl [64 * P];  // activations, 16 rows per wave
    __shared__ float bs[4 * 64];                          // b0 | b1 | b2 | W3

    const int tid  = threadIdx.x;
    const int o    = blockIdx.x / BPT;
    const int slot = blockIdx.x % BPT;

    // ---- stage tower weights into LDS, transposed + bf16 ----
    for (int idx = tid; idx < Idim * 64; idx += 256) {
        int i = idx >> 6, n = idx & 63;
        Wt0[n * P + i] = f2bf(W0[o * (Idim * 64) + idx]);   // coalesced read, scattered LDS write
    }
    for (int idx = tid; idx < 64 * 64; idx += 256) {
        int h = idx >> 6, n = idx & 63;
        Wt1[n * P + h] = f2bf(W1[o * 4096 + idx]);
        Wt2[n * P + h] = f2bf(W2[o * 4096 + idx]);
    }
    if (tid < 64) {
        bs[tid]       = b0[o * 64 + tid];
        bs[64 + tid]  = b1[o * 64 + tid];
        bs[128 + tid] = b2[o * 64 + tid];
        bs[192 + tid] = W3[o * 64 + tid];
    }
    __syncthreads();

    const int l = tid & 63, w = tid >> 6;
    const int c = l & 15,  g = l >> 4;   // MFMA lane coords: col / k-group

    // ---- hoist all weight B-fragments into registers (20 frags = 80 VGPR) ----
    bf8 wf0[4], wf1f[4][2], wf2f[4][2];
#pragma unroll
    for (int n = 0; n < 4; ++n) {
        wf0[n] = *(const bf8*)&Wt0[(n * 16 + c) * P + g * 8];
#pragma unroll
        for (int s = 0; s < 2; ++s) {
            wf1f[n][s] = *(const bf8*)&Wt1[(n * 16 + c) * P + s * 32 + g * 8];
            wf2f[n][s] = *(const bf8*)&Wt2[(n * 16 + c) * P + s * 32 + g * 8];
        }
    }
    float b0v[4], b1v[4], b2v[4], w3v[4];
#pragma unroll
    for (int n = 0; n < 4; ++n) {
        b0v[n] = bs[n * 16 + c];
        b1v[n] = bs[64 + n * 16 + c];
        b2v[n] = bs[128 + n * 16 + c];
        w3v[n] = bs[192 + n * 16 + c];
    }
    const float b3v = b3[o];

    const int hbase = w * 16 * P;        // this wave's private activation region
    const f32x4 z4 = {0.f, 0.f, 0.f, 0.f};

    for (int t = 0; t < ROWTILES; ++t) {
        const int tb = (slot * ROWTILES + t) * 64;

        // ---- L0 A-frag straight from global x (row = c, k = g*8+j) ----
        const float* xp = x + (tb + w * 16 + c) * Idim + g * 8;
        f32x4 xa = *(const f32x4*)xp;
        f32x4 xb = *(const f32x4*)(xp + 4);
        bf8 a0;
#pragma unroll
        for (int j = 0; j < 4; ++j) {
            a0[j]     = (short)f2bf(xa[j]);
            a0[4 + j] = (short)f2bf(xb[j]);
        }

        f32x4 acc[4];
#pragma unroll
        for (int n = 0; n < 4; ++n)
            acc[n] = __builtin_amdgcn_mfma_f32_16x16x32_bf16(a0, wf0[n], z4, 0, 0, 0);

        asm volatile("" ::: "memory");   // order vs prior-iteration LDS reads (WAR)
#pragma unroll
        for (int n = 0; n < 4; ++n)
#pragma unroll
            for (int r = 0; r < 4; ++r) {
                float v = fmaxf(acc[n][r] + b0v[n], 0.f);
                Hl[hbase + (g * 4 + r) * P + n * 16 + c] = f2bf(v);   // D: row=g*4+r, col=n*16+c
            }
        asm volatile("" ::: "memory");   // RAW through LDS within wave (DS pipe is in-order)

        // ---- L1 ----
        bf8 a1a = *(const bf8*)&Hl[hbase + c * P + g * 8];
        bf8 a1b = *(const bf8*)&Hl[hbase + c * P + 32 + g * 8];
#pragma unroll
        for (int n = 0; n < 4; ++n) {
            acc[n] = __builtin_amdgcn_mfma_f32_16x16x32_bf16(a1a, wf1f[n][0], z4, 0, 0, 0);
            acc[n] = __builtin_amdgcn_mfma_f32_16x16x32_bf16(a1b, wf1f[n][1], acc[n], 0, 0, 0);
        }
        asm volatile("" ::: "memory");
#pragma unroll
        for (int n = 0; n < 4; ++n)
#pragma unroll
            for (int r = 0; r < 4; ++r) {
                float v = fmaxf(acc[n][r] + b1v[n], 0.f);
                Hl[hbase + (g * 4 + r) * P + n * 16 + c] = f2bf(v);
            }
        asm volatile("" ::: "memory");

        // ---- L2 ----
        bf8 a2a = *(const bf8*)&Hl[hbase + c * P + g * 8];
        bf8 a2b = *(const bf8*)&Hl[hbase + c * P + 32 + g * 8];
#pragma unroll
        for (int n = 0; n < 4; ++n) {
            acc[n] = __builtin_amdgcn_mfma_f32_16x16x32_bf16(a2a, wf2f[n][0], z4, 0, 0, 0);
            acc[n] = __builtin_amdgcn_mfma_f32_16x16x32_bf16(a2b, wf2f[n][1], acc[n], 0, 0, 0);
        }

        // ---- L3: relu + dot(W3) on VALU, 16-lane group reduce ----
        float p0 = 0.f, p1 = 0.f, p2 = 0.f, p3 = 0.f;
#pragma unroll
        for (int n = 0; n < 4; ++n) {
            p0 += fmaxf(acc[n][0] + b2v[n], 0.f) * w3v[n];
            p1 += fmaxf(acc[n][1] + b2v[n], 0.f) * w3v[n];
            p2 += fmaxf(acc[n][2] + b2v[n], 0.f) * w3v[n];
            p3 += fmaxf(acc[n][3] + b2v[n], 0.f) * w3v[n];
        }
#pragma unroll
        for (int m = 1; m < 16; m <<= 1) {  // reduce across the 16 lanes sharing group g
            p0 += __shfl_xor(p0, m);
            p1 += __shfl_xor(p1, m);
            p2 += __shfl_xor(p2, m);
            p3 += __shfl_xor(p3, m);
        }
        if (c < 4) {
            float pv = (c == 0) ? p0 : (c == 1) ? p1 : (c == 2) ? p2 : p3;
            out[(tb + w * 16 + g * 4 + c) * Odim + o] = pv + b3v;  // row local = g*4 + c
        }
    }
}

extern "C" void kernel_launch(void* const* d_in, const int* in_sizes, int n_in,
                              void* d_out, int out_size, void* d_ws, size_t ws_size,
                              hipStream_t stream) {
    const float* x  = (const float*)d_in[0];
    const float* W0 = (const float*)d_in[1];
    const float* b0 = (const float*)d_in[2];
    const float* W1 = (const float*)d_in[3];
    const float* b1 = (const float*)d_in[4];
    const float* W2 = (const float*)d_in[5];
    const float* b2 = (const float*)d_in[6];
    const float* W3 = (const float*)d_in[7];
    const float* b3 = (const float*)d_in[8];
    float* out = (float*)d_out;

    dim3 grid(Odim * BPT);   // 64 towers x 32 blocks = 2048 blocks
    dim3 block(256);
    towers_kernel<<<grid, block, 0, stream>>>(x, W0, b0, W1, b1, W2, b2, W3, b3, out);
}

// Round 2
// 53.187 us; speedup vs baseline: 1.0557x; 1.0557x over previous
//
#include <hip/hip_runtime.h>

// DividedModel: 64 towers of Dense(32,64)+ReLU -> 64x64+ReLU -> 64x64+ReLU -> 64x1.
// R1: swapped-operand MFMA scheme. D = W^T * H^T puts col=batch in each lane, so
// inter-layer activations stay in registers; redistribution across k-groups is
// 2x permlane32_swap + 4x shfl_xor(16) + cndmask per 32-hidden half. Bias folds
// into the MFMA C operand. No LDS activity in the main loop at all.

typedef float  f32x4 __attribute__((ext_vector_type(4)));
typedef short  bf8   __attribute__((ext_vector_type(8)));
typedef unsigned int uint2v __attribute__((ext_vector_type(2)));
typedef unsigned int uint4v __attribute__((ext_vector_type(4)));

static constexpr int Bsz  = 16384;
static constexpr int Idim = 32;
static constexpr int Odim = 64;
static constexpr int BPT  = 32;                    // blocks per tower
static constexpr int ROWTILES = (Bsz / 64) / BPT;  // 8 tiles of 64 rows per block
static constexpr int P0 = 40;                      // Wt0 pitch (32 cols + pad, 80B rows, 16B-aligned)
static constexpr int P  = 72;                      // Wt1/Wt2 pitch (144B rows, 16B-aligned)

__device__ __forceinline__ unsigned short f2bf(float f) {   // staging only (one-time)
    unsigned int u = __builtin_bit_cast(unsigned int, f);
    unsigned int r = u + 0x7FFFu + ((u >> 16) & 1u);
    return (unsigned short)(r >> 16);
}

__device__ __forceinline__ unsigned cvt_pk(float lo, float hi) {  // 1 instr per bf16 pair
    unsigned d;
    asm("v_cvt_pk_bf16_f32 %0, %1, %2" : "=v"(d) : "v"(lo), "v"(hi));
    return d;
}

// Build next-layer B-frag (8 bf16 = k 8g..8g+7 of this lane's batch col) from the
// packed D of two 16-hidden chunks (pA = even chunk, pB = odd chunk; 2 dwords each).
__device__ __forceinline__ bf8 build_frag(unsigned pA0, unsigned pA1,
                                          unsigned pB0, unsigned pB1, bool odd) {
    uint2v s0 = __builtin_amdgcn_permlane32_swap(pA0, pB0, false, false);
    uint2v s1 = __builtin_amdgcn_permlane32_swap(pA1, pB1, false, false);
    unsigned X0 = s0.x, Y0 = s0.y;      // X = [A.lo|B.lo], Y = [A.hi|B.hi]
    unsigned X1 = s1.x, Y1 = s1.y;
    unsigned Xs0 = __shfl_xor(X0, 16), Xs1 = __shfl_xor(X1, 16);
    unsigned Ys0 = __shfl_xor(Y0, 16), Ys1 = __shfl_xor(Y1, 16);
    uint4v f;
    f.x = odd ? Ys0 : X0;
    f.y = odd ? Ys1 : X1;
    f.z = odd ? Y0  : Xs0;
    f.w = odd ? Y1  : Xs1;
    return __builtin_bit_cast(bf8, f);
}

__global__ __launch_bounds__(256) void towers_kernel(
    const float* __restrict__ x,
    const float* __restrict__ W0, const float* __restrict__ b0,
    const float* __restrict__ W1, const float* __restrict__ b1,
    const float* __restrict__ W2, const float* __restrict__ b2,
    const float* __restrict__ W3, const float* __restrict__ b3,
    float* __restrict__ out)
{
    __shared__ __align__(16) unsigned short Wt0[64 * P0]; // Wt0[h][i] = W0[o][i][h]
    __shared__ __align__(16) unsigned short Wt1[64 * P];  // Wt1[h][k] = W1[o][k][h]
    __shared__ __align__(16) unsigned short Wt2[64 * P];
    __shared__ __align__(16) float bs[4 * 64];            // b0 | b1 | b2 | W3

    const int tid  = threadIdx.x;
    const int o    = blockIdx.x / BPT;
    const int slot = blockIdx.x % BPT;

    // ---- one-time: stage tower weights into LDS, transposed + bf16 ----
    for (int idx = tid; idx < Idim * 64; idx += 256) {
        int i = idx >> 6, n = idx & 63;
        Wt0[n * P0 + i] = f2bf(W0[o * (Idim * 64) + idx]);
    }
    for (int idx = tid; idx < 64 * 64; idx += 256) {
        int h = idx >> 6, n = idx & 63;
        Wt1[n * P + h] = f2bf(W1[o * 4096 + idx]);
        Wt2[n * P + h] = f2bf(W2[o * 4096 + idx]);
    }
    if (tid < 64) {
        bs[tid]       = b0[o * 64 + tid];
        bs[64 + tid]  = b1[o * 64 + tid];
        bs[128 + tid] = b2[o * 64 + tid];
        bs[192 + tid] = W3[o * 64 + tid];
    }
    __syncthreads();

    const int l = tid & 63, w = tid >> 6;
    const int c = l & 15,  g = l >> 4;   // c: batch col / hidden-chunk row; g: k-group
    const bool odd = (g & 1);

    // ---- hoist weight A-frags: lane holds W^T[16n+c][8g+j] ----
    bf8 wf0[4], wf1f[4][2], wf2f[4][2];
#pragma unroll
    for (int n = 0; n < 4; ++n) {
        wf0[n] = *(const bf8*)&Wt0[(n * 16 + c) * P0 + g * 8];
#pragma unroll
        for (int s = 0; s < 2; ++s) {
            wf1f[n][s] = *(const bf8*)&Wt1[(n * 16 + c) * P + s * 32 + g * 8];
            wf2f[n][s] = *(const bf8*)&Wt2[(n * 16 + c) * P + s * 32 + g * 8];
        }
    }
    // ---- per-lane bias / w3 frags: element r of chunk n is hidden 16n+4g+r ----
    f32x4 b0f[4], b1f[4], b2f[4], w3f[4];
#pragma unroll
    for (int n = 0; n < 4; ++n) {
        b0f[n] = *(const f32x4*)&bs[      n * 16 + g * 4];
        b1f[n] = *(const f32x4*)&bs[ 64 + n * 16 + g * 4];
        b2f[n] = *(const f32x4*)&bs[128 + n * 16 + g * 4];
        w3f[n] = *(const f32x4*)&bs[192 + n * 16 + g * 4];
    }
    const float b3v = b3[o];

    for (int t = 0; t < ROWTILES; ++t) {
        const int tb = (slot * ROWTILES + t) * 64;

        // ---- L0: B-frag straight from global x (col=c=batch, k=8g+j) ----
        const float* xp = x + (tb + w * 16 + c) * Idim + g * 8;
        f32x4 xa = *(const f32x4*)xp;
        f32x4 xb = *(const f32x4*)(xp + 4);
        uint4v xd;
        xd.x = cvt_pk(xa[0], xa[1]); xd.y = cvt_pk(xa[2], xa[3]);
        xd.z = cvt_pk(xb[0], xb[1]); xd.w = cvt_pk(xb[2], xb[3]);
        bf8 a0 = __builtin_bit_cast(bf8, xd);

        f32x4 acc[4];
#pragma unroll
        for (int n = 0; n < 4; ++n)   // D[hidden=16n+4g+r][batch=c], bias in C
            acc[n] = __builtin_amdgcn_mfma_f32_16x16x32_bf16(wf0[n], a0, b0f[n], 0, 0, 0);

        // ---- relu + pack + redistribute -> L1 B-frags ----
        unsigned pk[4][2];
#pragma unroll
        for (int n = 0; n < 4; ++n) {
            pk[n][0] = cvt_pk(fmaxf(acc[n][0], 0.f), fmaxf(acc[n][1], 0.f));
            pk[n][1] = cvt_pk(fmaxf(acc[n][2], 0.f), fmaxf(acc[n][3], 0.f));
        }
        bf8 Blo = build_frag(pk[0][0], pk[0][1], pk[1][0], pk[1][1], odd);
        bf8 Bhi = build_frag(pk[2][0], pk[2][1], pk[3][0], pk[3][1], odd);

        // ---- L1 ----
#pragma unroll
        for (int n = 0; n < 4; ++n) {
            acc[n] = __builtin_amdgcn_mfma_f32_16x16x32_bf16(wf1f[n][0], Blo, b1f[n], 0, 0, 0);
            acc[n] = __builtin_amdgcn_mfma_f32_16x16x32_bf16(wf1f[n][1], Bhi, acc[n], 0, 0, 0);
        }
#pragma unroll
        for (int n = 0; n < 4; ++n) {
            pk[n][0] = cvt_pk(fmaxf(acc[n][0], 0.f), fmaxf(acc[n][1], 0.f));
            pk[n][1] = cvt_pk(fmaxf(acc[n][2], 0.f), fmaxf(acc[n][3], 0.f));
        }
        Blo = build_frag(pk[0][0], pk[0][1], pk[1][0], pk[1][1], odd);
        Bhi = build_frag(pk[2][0], pk[2][1], pk[3][0], pk[3][1], odd);

        // ---- L2 ----
#pragma unroll
        for (int n = 0; n < 4; ++n) {
            acc[n] = __builtin_amdgcn_mfma_f32_16x16x32_bf16(wf2f[n][0], Blo, b2f[n], 0, 0, 0);
            acc[n] = __builtin_amdgcn_mfma_f32_16x16x32_bf16(wf2f[n][1], Bhi, acc[n], 0, 0, 0);
        }

        // ---- L3: relu + dot(W3); reduce across the 4 k-groups ----
        float p = 0.f;
#pragma unroll
        for (int n = 0; n < 4; ++n) {
            p += fmaxf(acc[n][0], 0.f) * w3f[n][0];
            p += fmaxf(acc[n][1], 0.f) * w3f[n][1];
            p += fmaxf(acc[n][2], 0.f) * w3f[n][2];
            p += fmaxf(acc[n][3], 0.f) * w3f[n][3];
        }
        p += __shfl_xor(p, 16);
        p += __shfl_xor(p, 32);
        if (l < 16)
            out[(tb + w * 16 + l) * Odim + o] = p + b3v;
    }
}

extern "C" void kernel_launch(void* const* d_in, const int* in_sizes, int n_in,
                              void* d_out, int out_size, void* d_ws, size_t ws_size,
                              hipStream_t stream) {
    const float* x  = (const float*)d_in[0];
    const float* W0 = (const float*)d_in[1];
    const float* b0 = (const float*)d_in[2];
    const float* W1 = (const float*)d_in[3];
    const float* b1 = (const float*)d_in[4];
    const float* W2 = (const float*)d_in[5];
    const float* b2 = (const float*)d_in[6];
    const float* W3 = (const float*)d_in[7];
    const float* b3 = (const float*)d_in[8];
    float* out = (float*)d_out;

    dim3 grid(Odim * BPT);   // 64 towers x 32 blocks = 2048 blocks
    dim3 block(256);
    towers_kernel<<<grid, block, 0, stream>>>(x, W0, b0, W1, b1, W2, b2, W3, b3, out);
}

// Round 3
// 47.355 us; speedup vs baseline: 1.1857x; 1.1232x over previous
//
#include <hip/hip_runtime.h>

// DividedModel: 64 towers of Dense(32,64)+ReLU -> 64x64+ReLU -> 64x64+ReLU -> 64x1.
// R2: pi-trick. MFMA k-slot ordering is arbitrary as long as A and B agree, so the
// inter-layer B-frag is the lane's own packed accumulators (zero cross-lane ops);
// the compensating permutation S(in) is baked into the weight LDS staging.
// L3 is 2 MFMAs against a broadcast w3 A-frag (b3 folded into C). The main loop
// has NO LDS/DS traffic and no shuffles at all.

typedef float  f32x4 __attribute__((ext_vector_type(4)));
typedef short  bf8   __attribute__((ext_vector_type(8)));
typedef unsigned int uint4v __attribute__((ext_vector_type(4)));

static constexpr int Bsz  = 16384;
static constexpr int Idim = 32;
static constexpr int Odim = 64;
static constexpr int BPT  = 32;                    // blocks per tower
static constexpr int ROWTILES = (Bsz / 64) / BPT;  // 8 tiles of 64 rows per block
static constexpr int P0 = 40;                      // Wt0 pitch (80B rows, 16B-aligned)
static constexpr int P1 = 72;                      // Wt1/Wt2 pitch (144B rows, 16B-aligned)

__device__ __forceinline__ unsigned short f2bf(float f) {   // staging only (one-time)
    unsigned int u = __builtin_bit_cast(unsigned int, f);
    unsigned int r = u + 0x7FFFu + ((u >> 16) & 1u);
    return (unsigned short)(r >> 16);
}

__device__ __forceinline__ unsigned cvt_pk(float lo, float hi) {
    unsigned d;
    asm("v_cvt_pk_bf16_f32 %0, %1, %2" : "=v"(d) : "v"(lo), "v"(hi));
    return d;
}

// pi permutation: k-slot S for input-hidden index `in` (0..63).
// in_h(S) = 32*(S>>5) + 16*((S&7)>>2) + 4*((S>>3)&3) + (S&3); this is its inverse.
__device__ __forceinline__ int pi_slot(int in) {
    return 32 * (in >> 5) + 8 * ((in >> 2) & 3) + 4 * ((in >> 4) & 1) + (in & 3);
}

__global__ __launch_bounds__(256) void towers_kernel(
    const float* __restrict__ x,
    const float* __restrict__ W0, const float* __restrict__ b0,
    const float* __restrict__ W1, const float* __restrict__ b1,
    const float* __restrict__ W2, const float* __restrict__ b2,
    const float* __restrict__ W3, const float* __restrict__ b3,
    float* __restrict__ out)
{
    __shared__ __align__(16) unsigned short Wt0[64 * P0];  // Wt0[h][i]   = W0[o][i][h]  (natural k)
    __shared__ __align__(16) unsigned short Wt1[64 * P1];  // Wt1[h][S]   = W1[o][in(S)][h] (pi k)
    __shared__ __align__(16) unsigned short Wt2[64 * P1];
    __shared__ __align__(16) unsigned short w3s[64];       // w3s[S] = W3[o][in(S)]
    __shared__ __align__(16) float bs[3 * 64];             // b0 | b1 | b2

    const int tid  = threadIdx.x;
    const int o    = blockIdx.x / BPT;
    const int slot = blockIdx.x % BPT;

    // ---- one-time: stage tower weights into LDS (transposed, bf16, pi-permuted) ----
    for (int idx = tid; idx < Idim * 64; idx += 256) {
        int i = idx >> 6, h = idx & 63;
        Wt0[h * P0 + i] = f2bf(W0[o * (Idim * 64) + idx]);
    }
    for (int idx = tid; idx < 64 * 64; idx += 256) {
        int in = idx >> 6, h = idx & 63;
        int S = pi_slot(in);
        Wt1[h * P1 + S] = f2bf(W1[o * 4096 + idx]);
        Wt2[h * P1 + S] = f2bf(W2[o * 4096 + idx]);
    }
    if (tid < 64) {
        w3s[pi_slot(tid)] = f2bf(W3[o * 64 + tid]);
        bs[tid]       = b0[o * 64 + tid];
        bs[64 + tid]  = b1[o * 64 + tid];
        bs[128 + tid] = b2[o * 64 + tid];
    }
    __syncthreads();

    const int l = tid & 63, w = tid >> 6;
    const int c = l & 15,  g = l >> 4;   // c: batch col; g: k-group / D row-group

    // ---- hoist weight A-frags ----
    bf8 wf0[4], wf1f[4][2], wf2f[4][2];
#pragma unroll
    for (int n = 0; n < 4; ++n) {
        wf0[n] = *(const bf8*)&Wt0[(n * 16 + c) * P0 + g * 8];
#pragma unroll
        for (int s = 0; s < 2; ++s) {
            wf1f[n][s] = *(const bf8*)&Wt1[(n * 16 + c) * P1 + s * 32 + g * 8];
            wf2f[n][s] = *(const bf8*)&Wt2[(n * 16 + c) * P1 + s * 32 + g * 8];
        }
    }
    bf8 w3a[2];
    w3a[0] = *(const bf8*)&w3s[g * 8];        // wave-uniform per g (broadcast rows)
    w3a[1] = *(const bf8*)&w3s[32 + g * 8];

    // ---- bias C-frags: element r of chunk n is hidden 16n+4g+r ----
    f32x4 b0f[4], b1f[4], b2f[4];
#pragma unroll
    for (int n = 0; n < 4; ++n) {
        b0f[n] = *(const f32x4*)&bs[      n * 16 + g * 4];
        b1f[n] = *(const f32x4*)&bs[ 64 + n * 16 + g * 4];
        b2f[n] = *(const f32x4*)&bs[128 + n * 16 + g * 4];
    }
    const float b3v = b3[o];
    f32x4 c3 = {0.f, 0.f, 0.f, 0.f};
    if (g == 0) c3[0] = b3v;                  // b3 lands on D row 0 only

    for (int t = 0; t < ROWTILES; ++t) {
        const int tb = (slot * ROWTILES + t) * 64;

        // ---- L0: B-frag straight from global x (col=c=batch, k=8g+j, natural) ----
        const float* xp = x + (tb + w * 16 + c) * Idim + g * 8;
        f32x4 xa = *(const f32x4*)xp;
        f32x4 xb = *(const f32x4*)(xp + 4);
        uint4v xd;
        xd.x = cvt_pk(xa[0], xa[1]); xd.y = cvt_pk(xa[2], xa[3]);
        xd.z = cvt_pk(xb[0], xb[1]); xd.w = cvt_pk(xb[2], xb[3]);
        bf8 a0 = __builtin_bit_cast(bf8, xd);

        f32x4 acc[4];
#pragma unroll
        for (int n = 0; n < 4; ++n)   // D[hidden=16n+4g+r][batch=c], bias in C
            acc[n] = __builtin_amdgcn_mfma_f32_16x16x32_bf16(wf0[n], a0, b0f[n], 0, 0, 0);

        // ---- relu + pack: B-frags are lane-local thanks to pi-staged weights ----
        unsigned pk[4][2];
#pragma unroll
        for (int n = 0; n < 4; ++n) {
            pk[n][0] = cvt_pk(fmaxf(acc[n][0], 0.f), fmaxf(acc[n][1], 0.f));
            pk[n][1] = cvt_pk(fmaxf(acc[n][2], 0.f), fmaxf(acc[n][3], 0.f));
        }
        uint4v blo = {pk[0][0], pk[0][1], pk[1][0], pk[1][1]};
        uint4v bhi = {pk[2][0], pk[2][1], pk[3][0], pk[3][1]};
        bf8 Blo = __builtin_bit_cast(bf8, blo);
        bf8 Bhi = __builtin_bit_cast(bf8, bhi);

        // ---- L1 ----
#pragma unroll
        for (int n = 0; n < 4; ++n) {
            acc[n] = __builtin_amdgcn_mfma_f32_16x16x32_bf16(wf1f[n][0], Blo, b1f[n], 0, 0, 0);
            acc[n] = __builtin_amdgcn_mfma_f32_16x16x32_bf16(wf1f[n][1], Bhi, acc[n], 0, 0, 0);
        }
#pragma unroll
        for (int n = 0; n < 4; ++n) {
            pk[n][0] = cvt_pk(fmaxf(acc[n][0], 0.f), fmaxf(acc[n][1], 0.f));
            pk[n][1] = cvt_pk(fmaxf(acc[n][2], 0.f), fmaxf(acc[n][3], 0.f));
        }
        blo = uint4v{pk[0][0], pk[0][1], pk[1][0], pk[1][1]};
        bhi = uint4v{pk[2][0], pk[2][1], pk[3][0], pk[3][1]};
        Blo = __builtin_bit_cast(bf8, blo);
        Bhi = __builtin_bit_cast(bf8, bhi);

        // ---- L2 ----
#pragma unroll
        for (int n = 0; n < 4; ++n) {
            acc[n] = __builtin_amdgcn_mfma_f32_16x16x32_bf16(wf2f[n][0], Blo, b2f[n], 0, 0, 0);
            acc[n] = __builtin_amdgcn_mfma_f32_16x16x32_bf16(wf2f[n][1], Bhi, acc[n], 0, 0, 0);
        }
#pragma unroll
        for (int n = 0; n < 4; ++n) {
            pk[n][0] = cvt_pk(fmaxf(acc[n][0], 0.f), fmaxf(acc[n][1], 0.f));
            pk[n][1] = cvt_pk(fmaxf(acc[n][2], 0.f), fmaxf(acc[n][3], 0.f));
        }
        blo = uint4v{pk[0][0], pk[0][1], pk[1][0], pk[1][1]};
        bhi = uint4v{pk[2][0], pk[2][1], pk[3][0], pk[3][1]};
        Blo = __builtin_bit_cast(bf8, blo);
        Bhi = __builtin_bit_cast(bf8, bhi);

        // ---- L3: 2 MFMAs vs broadcast w3 rows; result row 0 = dot(relu(h2), w3)+b3 ----
        f32x4 acc3;
        acc3 = __builtin_amdgcn_mfma_f32_16x16x32_bf16(w3a[0], Blo, c3,   0, 0, 0);
        acc3 = __builtin_amdgcn_mfma_f32_16x16x32_bf16(w3a[1], Bhi, acc3, 0, 0, 0);

        if (g == 0)
            out[(tb + w * 16 + c) * Odim + o] = acc3[0];
    }
}

extern "C" void kernel_launch(void* const* d_in, const int* in_sizes, int n_in,
                              void* d_out, int out_size, void* d_ws, size_t ws_size,
                              hipStream_t stream) {
    const float* x  = (const float*)d_in[0];
    const float* W0 = (const float*)d_in[1];
    const float* b0 = (const float*)d_in[2];
    const float* W1 = (const float*)d_in[3];
    const float* b1 = (const float*)d_in[4];
    const float* W2 = (const float*)d_in[5];
    const float* b2 = (const float*)d_in[6];
    const float* W3 = (const float*)d_in[7];
    const float* b3 = (const float*)d_in[8];
    float* out = (float*)d_out;

    dim3 grid(Odim * BPT);   // 64 towers x 32 blocks = 2048 blocks
    dim3 block(256);
    towers_kernel<<<grid, block, 0, stream>>>(x, W0, b0, W1, b1, W2, b2, W3, b3, out);
}

// Round 4
// 44.246 us; speedup vs baseline: 1.2690x; 1.0703x over previous
//
#include <hip/hip_runtime.h>

// DividedModel: 64 towers of Dense(32,64)+ReLU -> 64x64+ReLU -> 64x64+ReLU -> 64x1.
// R3: R2's pi-trick scheme + 2-tile ILP interleave (two independent dependency
// chains per iteration), x-prefetch, float4 weight staging with XOR-swizzled
// LDS columns (kills the 8-way staging write conflicts).

typedef float  f32x4 __attribute__((ext_vector_type(4)));
typedef short  bf8   __attribute__((ext_vector_type(8)));
typedef unsigned int uint4v __attribute__((ext_vector_type(4)));

static constexpr int Bsz  = 16384;
static constexpr int Idim = 32;
static constexpr int Odim = 64;
static constexpr int BPT  = 32;                    // blocks per tower
static constexpr int ROWTILES = (Bsz / 64) / BPT;  // 8 tiles of 64 rows per block
static constexpr int P0 = 40;                      // Wt0 pitch (80B rows, 16B-aligned)
static constexpr int P1 = 72;                      // Wt1/Wt2 pitch (144B rows, 16B-aligned)

__device__ __forceinline__ unsigned short f2bf(float f) {   // staging only (one-time)
    unsigned int u = __builtin_bit_cast(unsigned int, f);
    unsigned int r = u + 0x7FFFu + ((u >> 16) & 1u);
    return (unsigned short)(r >> 16);
}

__device__ __forceinline__ unsigned cvt_pk(float lo, float hi) {
    unsigned d;
    asm("v_cvt_pk_bf16_f32 %0, %1, %2" : "=v"(d) : "v"(lo), "v"(hi));
    return d;
}

// pi permutation: k-slot S for input-hidden index `in` (0..63); self-inverse pair:
// in_h(S) = 32*(S>>5) + 16*((S&7)>>2) + 4*((S>>3)&3) + (S&3).
__device__ __forceinline__ int pi_slot(int in) {
    return 32 * (in >> 5) + 8 * ((in >> 2) & 3) + 4 * ((in >> 4) & 1) + (in & 3);
}

__global__ __launch_bounds__(256) void towers_kernel(
    const float* __restrict__ x,
    const float* __restrict__ W0, const float* __restrict__ b0,
    const float* __restrict__ W1, const float* __restrict__ b1,
    const float* __restrict__ W2, const float* __restrict__ b2,
    const float* __restrict__ W3, const float* __restrict__ b3,
    float* __restrict__ out)
{
    __shared__ __align__(16) unsigned short Wt0[64 * P0];  // Wt0[h][i^swz] = W0[o][i][h]
    __shared__ __align__(16) unsigned short Wt1[64 * P1];  // Wt1[h][S^swz] = W1[o][in(S)][h]
    __shared__ __align__(16) unsigned short Wt2[64 * P1];
    __shared__ __align__(16) unsigned short w3s[64];       // w3s[S] = W3[o][in(S)]
    __shared__ __align__(16) float bs[3 * 64];             // b0 | b1 | b2

    const int tid  = threadIdx.x;
    const int o    = blockIdx.x / BPT;
    const int slot = blockIdx.x % BPT;

    // ---- one-time staging: float4 loads, transposed bf16 writes, XOR-swizzled cols ----
    for (int f = tid; f < 512; f += 256) {                 // W0: 2048 floats
        f32x4 v = *(const f32x4*)&W0[o * 2048 + f * 4];
        int i  = (f * 4) >> 6;
        int h0 = (f * 4) & 63;
#pragma unroll
        for (int j = 0; j < 4; ++j) {
            int h = h0 + j;
            Wt0[h * P0 + (i ^ (((h >> 2) & 3) << 3))] = f2bf(v[j]);
        }
    }
    for (int f = tid; f < 1024; f += 256) {                // W1/W2: 4096 floats each
        f32x4 v1 = *(const f32x4*)&W1[o * 4096 + f * 4];
        f32x4 v2 = *(const f32x4*)&W2[o * 4096 + f * 4];
        int in = (f * 4) >> 6;
        int h0 = (f * 4) & 63;
        int S  = pi_slot(in);
#pragma unroll
        for (int j = 0; j < 4; ++j) {
            int h = h0 + j;
            int cw = S ^ (((h >> 2) & 7) << 3);
            Wt1[h * P1 + cw] = f2bf(v1[j]);
            Wt2[h * P1 + cw] = f2bf(v2[j]);
        }
    }
    if (tid < 64) {
        w3s[pi_slot(tid)] = f2bf(W3[o * 64 + tid]);
        bs[tid]       = b0[o * 64 + tid];
        bs[64 + tid]  = b1[o * 64 + tid];
        bs[128 + tid] = b2[o * 64 + tid];
    }
    __syncthreads();

    const int l = tid & 63, w = tid >> 6;
    const int c = l & 15,  g = l >> 4;   // c: batch col; g: k-group / D row-group

    // ---- hoist weight A-frags (apply the same XOR swizzle) ----
    bf8 wf0[4], wf1f[4][2], wf2f[4][2];
    {
        int k0 = (c >> 2) & 3;                         // W0 key, n-independent
#pragma unroll
        for (int n = 0; n < 4; ++n) {
            wf0[n] = *(const bf8*)&Wt0[(n * 16 + c) * P0 + ((g * 8) ^ (k0 << 3))];
            int k1 = ((c >> 2) + 4 * (n & 1)) & 7;     // W1/W2 key
#pragma unroll
            for (int s = 0; s < 2; ++s) {
                int col = (s * 32 + g * 8) ^ (k1 << 3);
                wf1f[n][s] = *(const bf8*)&Wt1[(n * 16 + c) * P1 + col];
                wf2f[n][s] = *(const bf8*)&Wt2[(n * 16 + c) * P1 + col];
            }
        }
    }
    bf8 w3a[2];
    w3a[0] = *(const bf8*)&w3s[g * 8];        // wave-uniform per g (broadcast rows)
    w3a[1] = *(const bf8*)&w3s[32 + g * 8];

    // ---- bias C-frags: element r of chunk n is hidden 16n+4g+r ----
    f32x4 b0f[4], b1f[4], b2f[4];
#pragma unroll
    for (int n = 0; n < 4; ++n) {
        b0f[n] = *(const f32x4*)&bs[      n * 16 + g * 4];
        b1f[n] = *(const f32x4*)&bs[ 64 + n * 16 + g * 4];
        b2f[n] = *(const f32x4*)&bs[128 + n * 16 + g * 4];
    }
    f32x4 c3 = {0.f, 0.f, 0.f, 0.f};
    if (g == 0) c3[0] = b3[o];                // b3 lands on D row 0 only

    // ---- main loop: 4 iterations x 2 independent tile-chains ----
    const float* xbase = x + (slot * ROWTILES * 64 + w * 16 + c) * Idim + g * 8;
    float* obase = out + (slot * ROWTILES * 64 + w * 16 + c) * Odim + o;

    f32x4 nxa0 = *(const f32x4*)(xbase);
    f32x4 nxb0 = *(const f32x4*)(xbase + 4);
    f32x4 nxa1 = *(const f32x4*)(xbase + 2048);
    f32x4 nxb1 = *(const f32x4*)(xbase + 2052);

    for (int tt = 0; tt < ROWTILES; tt += 2) {
        f32x4 xa0 = nxa0, xb0 = nxb0, xa1 = nxa1, xb1 = nxb1;
        if (tt + 2 < ROWTILES) {              // prefetch next pair
            const float* np = xbase + (tt + 2) * 2048;
            nxa0 = *(const f32x4*)(np);
            nxb0 = *(const f32x4*)(np + 4);
            nxa1 = *(const f32x4*)(np + 2048);
            nxb1 = *(const f32x4*)(np + 2052);
        }

        // ---- L0 B-frags from x ----
        uint4v xd0, xd1;
        xd0.x = cvt_pk(xa0[0], xa0[1]); xd0.y = cvt_pk(xa0[2], xa0[3]);
        xd0.z = cvt_pk(xb0[0], xb0[1]); xd0.w = cvt_pk(xb0[2], xb0[3]);
        xd1.x = cvt_pk(xa1[0], xa1[1]); xd1.y = cvt_pk(xa1[2], xa1[3]);
        xd1.z = cvt_pk(xb1[0], xb1[1]); xd1.w = cvt_pk(xb1[2], xb1[3]);
        bf8 a0_0 = __builtin_bit_cast(bf8, xd0);
        bf8 a0_1 = __builtin_bit_cast(bf8, xd1);

        f32x4 acc0[4], acc1[4];
#pragma unroll
        for (int n = 0; n < 4; ++n) {
            acc0[n] = __builtin_amdgcn_mfma_f32_16x16x32_bf16(wf0[n], a0_0, b0f[n], 0, 0, 0);
            acc1[n] = __builtin_amdgcn_mfma_f32_16x16x32_bf16(wf0[n], a0_1, b0f[n], 0, 0, 0);
        }

        // ---- relu + pack (lane-local thanks to pi staging) ----
        unsigned p0[4][2], p1[4][2];
#pragma unroll
        for (int n = 0; n < 4; ++n) {
            p0[n][0] = cvt_pk(fmaxf(acc0[n][0], 0.f), fmaxf(acc0[n][1], 0.f));
            p0[n][1] = cvt_pk(fmaxf(acc0[n][2], 0.f), fmaxf(acc0[n][3], 0.f));
            p1[n][0] = cvt_pk(fmaxf(acc1[n][0], 0.f), fmaxf(acc1[n][1], 0.f));
            p1[n][1] = cvt_pk(fmaxf(acc1[n][2], 0.f), fmaxf(acc1[n][3], 0.f));
        }
        bf8 Blo0 = __builtin_bit_cast(bf8, uint4v{p0[0][0], p0[0][1], p0[1][0], p0[1][1]});
        bf8 Bhi0 = __builtin_bit_cast(bf8, uint4v{p0[2][0], p0[2][1], p0[3][0], p0[3][1]});
        bf8 Blo1 = __builtin_bit_cast(bf8, uint4v{p1[0][0], p1[0][1], p1[1][0], p1[1][1]});
        bf8 Bhi1 = __builtin_bit_cast(bf8, uint4v{p1[2][0], p1[2][1], p1[3][0], p1[3][1]});

        // ---- L1 ----
#pragma unroll
        for (int n = 0; n < 4; ++n) {
            acc0[n] = __builtin_amdgcn_mfma_f32_16x16x32_bf16(wf1f[n][0], Blo0, b1f[n], 0, 0, 0);
            acc1[n] = __builtin_amdgcn_mfma_f32_16x16x32_bf16(wf1f[n][0], Blo1, b1f[n], 0, 0, 0);
            acc0[n] = __builtin_amdgcn_mfma_f32_16x16x32_bf16(wf1f[n][1], Bhi0, acc0[n], 0, 0, 0);
            acc1[n] = __builtin_amdgcn_mfma_f32_16x16x32_bf16(wf1f[n][1], Bhi1, acc1[n], 0, 0, 0);
        }
#pragma unroll
        for (int n = 0; n < 4; ++n) {
            p0[n][0] = cvt_pk(fmaxf(acc0[n][0], 0.f), fmaxf(acc0[n][1], 0.f));
            p0[n][1] = cvt_pk(fmaxf(acc0[n][2], 0.f), fmaxf(acc0[n][3], 0.f));
            p1[n][0] = cvt_pk(fmaxf(acc1[n][0], 0.f), fmaxf(acc1[n][1], 0.f));
            p1[n][1] = cvt_pk(fmaxf(acc1[n][2], 0.f), fmaxf(acc1[n][3], 0.f));
        }
        Blo0 = __builtin_bit_cast(bf8, uint4v{p0[0][0], p0[0][1], p0[1][0], p0[1][1]});
        Bhi0 = __builtin_bit_cast(bf8, uint4v{p0[2][0], p0[2][1], p0[3][0], p0[3][1]});
        Blo1 = __builtin_bit_cast(bf8, uint4v{p1[0][0], p1[0][1], p1[1][0], p1[1][1]});
        Bhi1 = __builtin_bit_cast(bf8, uint4v{p1[2][0], p1[2][1], p1[3][0], p1[3][1]});

        // ---- L2 ----
#pragma unroll
        for (int n = 0; n < 4; ++n) {
            acc0[n] = __builtin_amdgcn_mfma_f32_16x16x32_bf16(wf2f[n][0], Blo0, b2f[n], 0, 0, 0);
            acc1[n] = __builtin_amdgcn_mfma_f32_16x16x32_bf16(wf2f[n][0], Blo1, b2f[n], 0, 0, 0);
            acc0[n] = __builtin_amdgcn_mfma_f32_16x16x32_bf16(wf2f[n][1], Bhi0, acc0[n], 0, 0, 0);
            acc1[n] = __builtin_amdgcn_mfma_f32_16x16x32_bf16(wf2f[n][1], Bhi1, acc1[n], 0, 0, 0);
        }
#pragma unroll
        for (int n = 0; n < 4; ++n) {
            p0[n][0] = cvt_pk(fmaxf(acc0[n][0], 0.f), fmaxf(acc0[n][1], 0.f));
            p0[n][1] = cvt_pk(fmaxf(acc0[n][2], 0.f), fmaxf(acc0[n][3], 0.f));
            p1[n][0] = cvt_pk(fmaxf(acc1[n][0], 0.f), fmaxf(acc1[n][1], 0.f));
            p1[n][1] = cvt_pk(fmaxf(acc1[n][2], 0.f), fmaxf(acc1[n][3], 0.f));
        }
        Blo0 = __builtin_bit_cast(bf8, uint4v{p0[0][0], p0[0][1], p0[1][0], p0[1][1]});
        Bhi0 = __builtin_bit_cast(bf8, uint4v{p0[2][0], p0[2][1], p0[3][0], p0[3][1]});
        Blo1 = __builtin_bit_cast(bf8, uint4v{p1[0][0], p1[0][1], p1[1][0], p1[1][1]});
        Bhi1 = __builtin_bit_cast(bf8, uint4v{p1[2][0], p1[2][1], p1[3][0], p1[3][1]});

        // ---- L3: 2 MFMAs per tile vs broadcast w3 rows; row 0 = dot + b3 ----
        f32x4 acc3_0, acc3_1;
        acc3_0 = __builtin_amdgcn_mfma_f32_16x16x32_bf16(w3a[0], Blo0, c3,     0, 0, 0);
        acc3_1 = __builtin_amdgcn_mfma_f32_16x16x32_bf16(w3a[0], Blo1, c3,     0, 0, 0);
        acc3_0 = __builtin_amdgcn_mfma_f32_16x16x32_bf16(w3a[1], Bhi0, acc3_0, 0, 0, 0);
        acc3_1 = __builtin_amdgcn_mfma_f32_16x16x32_bf16(w3a[1], Bhi1, acc3_1, 0, 0, 0);

        if (g == 0) {
            obase[(tt)     * 64 * Odim] = acc3_0[0];
            obase[(tt + 1) * 64 * Odim] = acc3_1[0];
        }
    }
}

extern "C" void kernel_launch(void* const* d_in, const int* in_sizes, int n_in,
                              void* d_out, int out_size, void* d_ws, size_t ws_size,
                              hipStream_t stream) {
    const float* x  = (const float*)d_in[0];
    const float* W0 = (const float*)d_in[1];
    const float* b0 = (const float*)d_in[2];
    const float* W1 = (const float*)d_in[3];
    const float* b1 = (const float*)d_in[4];
    const float* W2 = (const float*)d_in[5];
    const float* b2 = (const float*)d_in[6];
    const float* W3 = (const float*)d_in[7];
    const float* b3 = (const float*)d_in[8];
    float* out = (float*)d_out;

    dim3 grid(Odim * BPT);   // 64 towers x 32 blocks = 2048 blocks
    dim3 block(256);
    towers_kernel<<<grid, block, 0, stream>>>(x, W0, b0, W1, b1, W2, b2, W3, b3, out);
}

// Round 5
// 40.123 us; speedup vs baseline: 1.3994x; 1.1028x over previous
//
#include <hip/hip_runtime.h>

// DividedModel: 64 towers of Dense(32,64)+ReLU -> 64x64+ReLU -> 64x64+ReLU -> 64x1.
// R4: register-diet for occupancy. Persistent regs: W1 frags + w3 + biases only.
// W0/W2 frags re-read from LDS每tile (laundered indices to defeat LICM). 1-tile
// chain, pi-trick (zero cross-lane), bias-in-C, L3-as-MFMA. XOR key ((h>>2)^h)
// gives 2-way (free) bank access on both staging writes and in-loop b128 reads.

typedef float  f32x4 __attribute__((ext_vector_type(4)));
typedef short  bf8   __attribute__((ext_vector_type(8)));
typedef unsigned int uint4v __attribute__((ext_vector_type(4)));

static constexpr int Bsz  = 16384;
static constexpr int Idim = 32;
static constexpr int Odim = 64;
static constexpr int BPT  = 32;                    // blocks per tower
static constexpr int ROWTILES = (Bsz / 64) / BPT;  // 8 tiles of 64 rows per block

__device__ __forceinline__ unsigned short f2bf(float f) {   // staging only (one-time)
    unsigned int u = __builtin_bit_cast(unsigned int, f);
    unsigned int r = u + 0x7FFFu + ((u >> 16) & 1u);
    return (unsigned short)(r >> 16);
}

__device__ __forceinline__ unsigned cvt_pk(float lo, float hi) {
    unsigned d;
    asm("v_cvt_pk_bf16_f32 %0, %1, %2" : "=v"(d) : "v"(lo), "v"(hi));
    return d;
}

// pi permutation: k-slot S for input-hidden index `in` (0..63).
// in_h(S) = 32*(S>>5) + 16*((S&7)>>2) + 4*((S>>3)&3) + (S&3).
__device__ __forceinline__ int pi_slot(int in) {
    return 32 * (in >> 5) + 8 * ((in >> 2) & 3) + 4 * ((in >> 4) & 1) + (in & 3);
}

__global__ __launch_bounds__(256, 3) void towers_kernel(
    const float* __restrict__ x,
    const float* __restrict__ W0, const float* __restrict__ b0,
    const float* __restrict__ W1, const float* __restrict__ b1,
    const float* __restrict__ W2, const float* __restrict__ b2,
    const float* __restrict__ W3, const float* __restrict__ b3,
    float* __restrict__ out)
{
    __shared__ __align__(16) unsigned short Wt0[64 * 32];  // 4KB,  Wt0[h][i^swz]
    __shared__ __align__(16) unsigned short Wt1[64 * 64];  // 8KB,  Wt1[h][S^swz]
    __shared__ __align__(16) unsigned short Wt2[64 * 64];  // 8KB
    __shared__ __align__(16) unsigned short w3s[64];       // w3s[S] = W3[o][in(S)]
    __shared__ __align__(16) float bs[3 * 64];             // b0 | b1 | b2

    const int tid  = threadIdx.x;
    const int o    = blockIdx.x / BPT;
    const int slot = blockIdx.x % BPT;

    // ---- one-time staging: float4 loads, transposed bf16, XOR-swizzled cols ----
    for (int f = tid; f < 512; f += 256) {                 // W0: 2048 floats
        f32x4 v = *(const f32x4*)&W0[o * 2048 + f * 4];
        int i  = (f * 4) >> 6;
        int h0 = (f * 4) & 63;
#pragma unroll
        for (int j = 0; j < 4; ++j) {
            int h = h0 + j;
            Wt0[h * 32 + (i ^ ((((h >> 2) ^ h) & 3) << 3))] = f2bf(v[j]);
        }
    }
    for (int f = tid; f < 1024; f += 256) {                // W1/W2: 4096 floats each
        f32x4 v1 = *(const f32x4*)&W1[o * 4096 + f * 4];
        f32x4 v2 = *(const f32x4*)&W2[o * 4096 + f * 4];
        int in = (f * 4) >> 6;
        int h0 = (f * 4) & 63;
        int S  = pi_slot(in);
#pragma unroll
        for (int j = 0; j < 4; ++j) {
            int h = h0 + j;
            int cw = S ^ ((((h >> 2) ^ h) & 7) << 3);
            Wt1[h * 64 + cw] = f2bf(v1[j]);
            Wt2[h * 64 + cw] = f2bf(v2[j]);
        }
    }
    if (tid < 64) {
        w3s[pi_slot(tid)] = f2bf(W3[o * 64 + tid]);
        bs[tid]       = b0[o * 64 + tid];
        bs[64 + tid]  = b1[o * 64 + tid];
        bs[128 + tid] = b2[o * 64 + tid];
    }
    __syncthreads();

    const int l = tid & 63, w = tid >> 6;
    const int c = l & 15,  g = l >> 4;   // c: batch col; g: k-group / D row-group

    // ---- persistent regs: W1 frags (32), w3 (8), biases (48), c3 (4) ----
    bf8 wf1f[4][2];
#pragma unroll
    for (int n = 0; n < 4; ++n) {
        int h = n * 16 + c;
        int key = ((h >> 2) ^ h) & 7;
#pragma unroll
        for (int s = 0; s < 2; ++s)
            wf1f[n][s] = *(const bf8*)&Wt1[h * 64 + ((s * 32 + g * 8) ^ (key << 3))];
    }
    bf8 w3a[2];
    w3a[0] = *(const bf8*)&w3s[g * 8];        // wave-uniform per g (broadcast rows)
    w3a[1] = *(const bf8*)&w3s[32 + g * 8];

    f32x4 b0f[4], b1f[4], b2f[4];
#pragma unroll
    for (int n = 0; n < 4; ++n) {
        b0f[n] = *(const f32x4*)&bs[      n * 16 + g * 4];
        b1f[n] = *(const f32x4*)&bs[ 64 + n * 16 + g * 4];
        b2f[n] = *(const f32x4*)&bs[128 + n * 16 + g * 4];
    }
    f32x4 c3 = {0.f, 0.f, 0.f, 0.f};
    if (g == 0) c3[0] = b3[o];                // b3 lands on D row 0 only

    const float* xbase = x + (slot * ROWTILES * 64 + w * 16 + c) * Idim + g * 8;
    float* obase = out + (slot * ROWTILES * 64 + w * 16 + c) * Odim + o;

    f32x4 nxa = *(const f32x4*)(xbase);
    f32x4 nxb = *(const f32x4*)(xbase + 4);

    for (int t = 0; t < ROWTILES; ++t) {
        f32x4 xa = nxa, xb = nxb;
        if (t + 1 < ROWTILES) {               // prefetch next tile's x
            const float* np = xbase + (t + 1) * 2048;
            nxa = *(const f32x4*)(np);
            nxb = *(const f32x4*)(np + 4);
        }

        // ---- L0 B-frag from x ----
        uint4v xd;
        xd.x = cvt_pk(xa[0], xa[1]); xd.y = cvt_pk(xa[2], xa[3]);
        xd.z = cvt_pk(xb[0], xb[1]); xd.w = cvt_pk(xb[2], xb[3]);
        bf8 a0 = __builtin_bit_cast(bf8, xd);

        // ---- W0 frags from LDS (laundered: defeat LICM, stay transient) ----
        bf8 wf0[4];
#pragma unroll
        for (int n = 0; n < 4; ++n) {
            int h = n * 16 + c;
            int idx = h * 32 + ((g * 8) ^ ((((h >> 2) ^ h) & 3) << 3));
            asm volatile("" : "+v"(idx));
            wf0[n] = *(const bf8*)&Wt0[idx];
        }

        f32x4 acc[4];
#pragma unroll
        for (int n = 0; n < 4; ++n)   // D[hidden=16n+4g+r][batch=c], bias in C
            acc[n] = __builtin_amdgcn_mfma_f32_16x16x32_bf16(wf0[n], a0, b0f[n], 0, 0, 0);

        // ---- relu + pack (lane-local thanks to pi staging) ----
        unsigned pk[4][2];
#pragma unroll
        for (int n = 0; n < 4; ++n) {
            pk[n][0] = cvt_pk(fmaxf(acc[n][0], 0.f), fmaxf(acc[n][1], 0.f));
            pk[n][1] = cvt_pk(fmaxf(acc[n][2], 0.f), fmaxf(acc[n][3], 0.f));
        }
        bf8 Blo = __builtin_bit_cast(bf8, uint4v{pk[0][0], pk[0][1], pk[1][0], pk[1][1]});
        bf8 Bhi = __builtin_bit_cast(bf8, uint4v{pk[2][0], pk[2][1], pk[3][0], pk[3][1]});

        // ---- L1 (weights in regs) ----
#pragma unroll
        for (int n = 0; n < 4; ++n)
            acc[n] = __builtin_amdgcn_mfma_f32_16x16x32_bf16(wf1f[n][0], Blo, b1f[n], 0, 0, 0);
#pragma unroll
        for (int n = 0; n < 4; ++n)
            acc[n] = __builtin_amdgcn_mfma_f32_16x16x32_bf16(wf1f[n][1], Bhi, acc[n], 0, 0, 0);
#pragma unroll
        for (int n = 0; n < 4; ++n) {
            pk[n][0] = cvt_pk(fmaxf(acc[n][0], 0.f), fmaxf(acc[n][1], 0.f));
            pk[n][1] = cvt_pk(fmaxf(acc[n][2], 0.f), fmaxf(acc[n][3], 0.f));
        }
        Blo = __builtin_bit_cast(bf8, uint4v{pk[0][0], pk[0][1], pk[1][0], pk[1][1]});
        Bhi = __builtin_bit_cast(bf8, uint4v{pk[2][0], pk[2][1], pk[3][0], pk[3][1]});

        // ---- L2 (weights from LDS, two transient groups of 4 frags) ----
        {
            bf8 w2[4];
#pragma unroll
            for (int n = 0; n < 4; ++n) {
                int h = n * 16 + c;
                int idx = h * 64 + ((g * 8) ^ ((((h >> 2) ^ h) & 7) << 3));
                asm volatile("" : "+v"(idx));
                w2[n] = *(const bf8*)&Wt2[idx];
            }
#pragma unroll
            for (int n = 0; n < 4; ++n)
                acc[n] = __builtin_amdgcn_mfma_f32_16x16x32_bf16(w2[n], Blo, b2f[n], 0, 0, 0);
#pragma unroll
            for (int n = 0; n < 4; ++n) {
                int h = n * 16 + c;
                int idx = h * 64 + (((32 + g * 8)) ^ ((((h >> 2) ^ h) & 7) << 3));
                asm volatile("" : "+v"(idx));
                w2[n] = *(const bf8*)&Wt2[idx];
            }
#pragma unroll
            for (int n = 0; n < 4; ++n)
                acc[n] = __builtin_amdgcn_mfma_f32_16x16x32_bf16(w2[n], Bhi, acc[n], 0, 0, 0);
        }
#pragma unroll
        for (int n = 0; n < 4; ++n) {
            pk[n][0] = cvt_pk(fmaxf(acc[n][0], 0.f), fmaxf(acc[n][1], 0.f));
            pk[n][1] = cvt_pk(fmaxf(acc[n][2], 0.f), fmaxf(acc[n][3], 0.f));
        }
        Blo = __builtin_bit_cast(bf8, uint4v{pk[0][0], pk[0][1], pk[1][0], pk[1][1]});
        Bhi = __builtin_bit_cast(bf8, uint4v{pk[2][0], pk[2][1], pk[3][0], pk[3][1]});

        // ---- L3: 2 MFMAs vs broadcast w3 rows; row 0 = dot(relu(h2), w3)+b3 ----
        f32x4 acc3;
        acc3 = __builtin_amdgcn_mfma_f32_16x16x32_bf16(w3a[0], Blo, c3,   0, 0, 0);
        acc3 = __builtin_amdgcn_mfma_f32_16x16x32_bf16(w3a[1], Bhi, acc3, 0, 0, 0);

        if (g == 0)
            obase[t * 64 * Odim] = acc3[0];
    }
}

extern "C" void kernel_launch(void* const* d_in, const int* in_sizes, int n_in,
                              void* d_out, int out_size, void* d_ws, size_t ws_size,
                              hipStream_t stream) {
    const float* x  = (const float*)d_in[0];
    const float* W0 = (const float*)d_in[1];
    const float* b0 = (const float*)d_in[2];
    const float* W1 = (const float*)d_in[3];
    const float* b1 = (const float*)d_in[4];
    const float* W2 = (const float*)d_in[5];
    const float* b2 = (const float*)d_in[6];
    const float* W3 = (const float*)d_in[7];
    const float* b3 = (const float*)d_in[8];
    float* out = (float*)d_out;

    dim3 grid(Odim * BPT);   // 64 towers x 32 blocks = 2048 blocks
    dim3 block(256);
    towers_kernel<<<grid, block, 0, stream>>>(x, W0, b0, W1, b1, W2, b2, W3, b3, out);
}